// Round 6
// baseline (526.160 us; speedup 1.0000x reference)
//
#include <hip/hip_runtime.h>
#include <hip/hip_bf16.h>

#define NN   50000   // nodes
#define NE   50000   // hyperedges
#define NNZV 500000
#define NG   50
#define INC  128
#define HID  256
#define OUTC 2
#define STRIDE 32    // one aligned 64B line per segment

typedef __bf16 bf16_t;
typedef __bf16 bf16x8 __attribute__((ext_vector_type(8)));
typedef float  f32x4  __attribute__((ext_vector_type(4)));
typedef float  f32x2  __attribute__((ext_vector_type(2)));

__device__ __forceinline__ bf16_t f2b(float f) {
  union { __hip_bfloat16 h; bf16_t b; } u;
  u.h = __float2bfloat16(f);
  return u.b;
}
__device__ __forceinline__ float b2f(bf16_t b) { return (float)b; }

// fp8 e4m3 (OCP) pack/unpack; word-select must be an immediate -> template param.
template <bool HI>
__device__ __forceinline__ unsigned int fp8_pk2(float a, float b, unsigned int old) {
  return __builtin_amdgcn_cvt_pk_fp8_f32(a, b, old, HI);
}
__device__ __forceinline__ uint4 fp8_pk16(const float* v) {
  uint4 o;
  unsigned int* ow = &o.x;
#pragma unroll
  for (int wd = 0; wd < 4; wd++) {
    unsigned int u = fp8_pk2<false>(v[wd * 4 + 0], v[wd * 4 + 1], 0u);
    ow[wd] = fp8_pk2<true>(v[wd * 4 + 2], v[wd * 4 + 3], u);
  }
  return o;
}
__device__ __forceinline__ void fp8_acc16(uint4 v, f32x2* a2) {
  a2[0] += __builtin_amdgcn_cvt_pk_f32_fp8(v.x, false);
  a2[1] += __builtin_amdgcn_cvt_pk_f32_fp8(v.x, true);
  a2[2] += __builtin_amdgcn_cvt_pk_f32_fp8(v.y, false);
  a2[3] += __builtin_amdgcn_cvt_pk_f32_fp8(v.y, true);
  a2[4] += __builtin_amdgcn_cvt_pk_f32_fp8(v.z, false);
  a2[5] += __builtin_amdgcn_cvt_pk_f32_fp8(v.z, true);
  a2[6] += __builtin_amdgcn_cvt_pk_f32_fp8(v.w, false);
  a2[7] += __builtin_amdgcn_cvt_pk_f32_fp8(v.w, true);
}

// ------------------------- build: fill(x2) ∥ xcast(fp8) ∥ wswiz ∥ gstart ---------------------
// (R4-proven structure; the R5 build/e0 split regressed — ride-along fill blocks serialized
// after the gather blocks instead of overlapping.)
__device__ __forceinline__ void wswiz_one(const float* __restrict__ W, bf16_t* __restrict__ wsw, int t) {
  int lane = t & 63;
  int nt   = (t >> 6) & 15;
  int kc   = t >> 10;
  int q = lane >> 4, n16 = lane & 15;
  bf16x8 o;
#pragma unroll
  for (int j = 0; j < 8; j++)
    o[j] = f2b(W[(size_t)(kc * 32 + q * 8 + j) * HID + nt * 16 + n16]);
  reinterpret_cast<bf16x8*>(wsw)[t] = o;
}

#define FILL_EPT   4
#define FILL_CHUNK (256 * FILL_EPT)                       // 1024 edges per block
#define FILL_B     ((NNZV + FILL_CHUNK - 1) / FILL_CHUNK) // 489 per side
#define PREP_BX 1563   // xcast blocks
#define PREP_BW 80     // wswiz blocks
#define PREP_BG 196    // gstart blocks

__device__ __forceinline__ void fill_side(const int* __restrict__ keys, const int* __restrict__ vals,
                                          int* __restrict__ cur, unsigned short* __restrict__ lstd,
                                          int local) {
  int base = local * FILL_CHUNK + threadIdx.x;
  int key[FILL_EPT], val[FILL_EPT], slot[FILL_EPT];
  bool ok[FILL_EPT];
#pragma unroll
  for (int e = 0; e < FILL_EPT; e++) {
    int i  = base + e * 256;
    ok[e]  = (i < NNZV);
    int ii = ok[e] ? i : 0;
    key[e] = keys[ii];
    val[e] = vals[ii];
  }
#pragma unroll
  for (int e = 0; e < FILL_EPT; e++)
    if (ok[e]) slot[e] = atomicAdd(&cur[key[e]], 1);
#pragma unroll
  for (int e = 0; e < FILL_EPT; e++)
    if (ok[e] && slot[e] < STRIDE)
      lstd[((size_t)key[e] << 5) + slot[e]] = (unsigned short)val[e];
}

__global__ void build_kernel(const int* __restrict__ rows, const int* __restrict__ cols,
                             int* __restrict__ ncur, int* __restrict__ ecur,
                             unsigned short* __restrict__ ncol, unsigned short* __restrict__ erow,
                             const float* __restrict__ x, unsigned char* __restrict__ xb8,
                             const float* __restrict__ W0, const float* __restrict__ W1,
                             const float* __restrict__ W2, bf16_t* __restrict__ w0,
                             bf16_t* __restrict__ w1, bf16_t* __restrict__ w2,
                             const int* __restrict__ batch, int* __restrict__ gstart) {
  int blk = blockIdx.x;
  if (blk < 2 * FILL_B) {
    if (blk < FILL_B) fill_side(cols, rows, ecur, erow, blk);             // edge-side
    else              fill_side(rows, cols, ncur, ncol, blk - FILL_B);    // node-side
  } else if (blk < 2 * FILL_B + PREP_BX) {
    int t = (blk - 2 * FILL_B) * 256 + threadIdx.x;
    if (t >= NN * INC / 16) return;
    const f32x4* p = reinterpret_cast<const f32x4*>(x) + (size_t)t * 4;
    float v[16];
#pragma unroll
    for (int wd = 0; wd < 4; wd++) {
      f32x4 q4 = p[wd];
#pragma unroll
      for (int j = 0; j < 4; j++) v[wd * 4 + j] = q4[j];
    }
    reinterpret_cast<uint4*>(xb8)[t] = fp8_pk16(v);
  } else if (blk < 2 * FILL_B + PREP_BX + PREP_BW) {
    int t = (blk - 2 * FILL_B - PREP_BX) * 256 + threadIdx.x;
    const int C0 = (INC / 32) * 1024;   // 4096
    const int C1 = (HID / 32) * 1024;   // 8192
    if (t < C0)                wswiz_one(W0, w0, t);
    else if (t < C0 + C1)      wswiz_one(W1, w1, t - C0);
    else if (t < C0 + 2 * C1)  wswiz_one(W2, w2, t - C0 - C1);
  } else {
    int i = (blk - 2 * FILL_B - PREP_BX - PREP_BW) * 256 + threadIdx.x;
    if (i >= NN) return;
    int cur  = batch[i];
    int prev = (i == 0) ? -1 : batch[i - 1];
    for (int g = prev + 1; g <= cur; g++) gstart[g] = i;
    if (i == NN - 1) {
      for (int g = cur + 1; g <= NG; g++) gstart[g] = NN;
    }
  }
}

// --------------- feature-sliced gather: slice = blockIdx & 7 -> XCD-resident source ----------
// Gather is independent per feature. Slice s covers K/8 features; blocks with (blk&7)==s land
// on XCD s (default round-robin dispatch), so each XCD's random-read working set is
// NN x (K/8) bytes (3.2 MB at K=256) -> fits the 4 MB per-XCD L2. Re-reads (mean degree ~10)
// become L2 hits instead of HBM misses. Each thread owns one (segment, 16B sub-slice):
// 64B list loaded upfront (one wait), feature loads double-buffered 8-deep.
template <int K, bool OUT8, bool BR>
__global__ __launch_bounds__(256) void sgath_kernel(const unsigned char* __restrict__ src,
                                                    const int* __restrict__ cnt,
                                                    const unsigned short* __restrict__ lst,
                                                    const float* __restrict__ bias,
                                                    void* __restrict__ dst, int nseg) {
  constexpr int SLB  = K / 8;      // slice width in features (= bytes of fp8 src)
  constexpr int LS   = SLB / 16;   // threads per segment (16B granules per slice)
  constexpr int SPB  = 256 / LS;   // segments per block
  constexpr int RSTR = K / 16;     // uint4 per source row
  const int slice = blockIdx.x & 7;
  const int tile  = blockIdx.x >> 3;
  const int t     = threadIdx.x;
  const int seg   = tile * SPB + t / LS;
  const int lr    = t % LS;
  if (seg >= nseg) return;
  const int fo = slice * SLB + lr * 16;   // feature offset (fp8 byte offset in row)
  int c = min(cnt[seg], STRIDE);
  const uint4* lp = reinterpret_cast<const uint4*>(lst + ((size_t)seg << 5));
  uint4 la = lp[0], lb = lp[1], lc4 = lp[2], ld = lp[3];
  unsigned int lw[16] = {la.x, la.y, la.z, la.w, lb.x, lb.y, lb.z, lb.w,
                         lc4.x, lc4.y, lc4.z, lc4.w, ld.x, ld.y, ld.z, ld.w};
  const uint4* sv = reinterpret_cast<const uint4*>(src) + (fo >> 4);
  float acc[16];
  f32x2* a2 = reinterpret_cast<f32x2*>(acc);
#pragma unroll
  for (int k = 0; k < 8; k++) a2[k] = f32x2{0.f, 0.f};
  uint4 v0[8], v1[8];
#define GADDR(j) ((size_t)((lw[(j) >> 1] >> (((j) & 1) * 16)) & 0xffffu) * RSTR)
#pragma unroll
  for (int j = 0; j < 8; j++) if (j < c) v0[j] = sv[GADDR(j)];
#pragma unroll
  for (int j = 0; j < 8; j++) if (8 + j < c) v1[j] = sv[GADDR(8 + j)];
#pragma unroll
  for (int j = 0; j < 8; j++) if (j < c) fp8_acc16(v0[j], a2);
#pragma unroll
  for (int j = 0; j < 8; j++) if (16 + j < c) v0[j] = sv[GADDR(16 + j)];
#pragma unroll
  for (int j = 0; j < 8; j++) if (8 + j < c) fp8_acc16(v1[j], a2);
#pragma unroll
  for (int j = 0; j < 8; j++) if (24 + j < c) v1[j] = sv[GADDR(24 + j)];
#pragma unroll
  for (int j = 0; j < 8; j++) if (16 + j < c) fp8_acc16(v0[j], a2);
#pragma unroll
  for (int j = 0; j < 8; j++) if (24 + j < c) fp8_acc16(v1[j], a2);
#undef GADDR
  float sc = (c > 0) ? (1.0f / (float)c) : 0.f;
  float v16[16];
#pragma unroll
  for (int k = 0; k < 16; k++) {
    float v = acc[k] * sc;
    if constexpr (BR) v = fmaxf(v + bias[fo + k], 0.f);
    v16[k] = v;
  }
  if constexpr (OUT8) {
    *reinterpret_cast<uint4*>((unsigned char*)dst + (size_t)seg * K + fo) = fp8_pk16(v16);
  } else {
    bf16_t* dp = (bf16_t*)dst + (size_t)seg * K + fo;
    bf16x8 o0, o1;
#pragma unroll
    for (int k = 0; k < 8; k++) { o0[k] = f2b(v16[k]); o1[k] = f2b(v16[k + 8]); }
    reinterpret_cast<bf16x8*>(dp)[0] = o0;
    reinterpret_cast<bf16x8*>(dp)[1] = o1;
  }
}

// -------- streaming double GEMM: N0(bf16) @ W0 (+b0,relu) @ W1 -> fp8, 32 rows/block ---------
__global__ __launch_bounds__(256) void gemm01_kernel(const bf16_t* __restrict__ A,
                                                     const bf16_t* __restrict__ wswA,
                                                     const float* __restrict__ biasA,
                                                     const bf16_t* __restrict__ wswB,
                                                     unsigned char* __restrict__ Bout, int M) {
  constexpr int K   = INC;
  constexpr int SW  = K + 8;
  constexpr int SW2 = HID + 8;
  __shared__ bf16_t arows[32 * SW];
  __shared__ bf16_t brows[32 * SW2];
  const int tid  = threadIdx.x;
  const int wid  = tid >> 6;
  const int lane = tid & 63;
  const int mblk = blockIdx.x * 32;

  // stage 32 rows x 128 bf16 (coalesced)
#pragma unroll
  for (int i = 0; i < 2; i++) {
    int idx = tid + i * 256;          // 0..511
    int row = idx >> 4, u = idx & 15;
    if (mblk + row < M)
      *reinterpret_cast<uint4*>(arows + row * SW + u * 8) =
          *reinterpret_cast<const uint4*>(A + (size_t)(mblk + row) * K + u * 8);
  }
  __syncthreads();

  const int q = lane >> 4, n16 = lane & 15;
  {
    f32x4 acc2[2][4];
#pragma unroll
    for (int a = 0; a < 2; a++)
#pragma unroll
      for (int j = 0; j < 4; j++) acc2[a][j] = f32x4{0.f, 0.f, 0.f, 0.f};
    const bf16x8* wv = reinterpret_cast<const bf16x8*>(wswA);
    for (int kc = 0; kc < K / 32; kc++) {
      bf16x8 af0 = *reinterpret_cast<const bf16x8*>(arows + n16 * SW + kc * 32 + q * 8);
      bf16x8 af1 = *reinterpret_cast<const bf16x8*>(arows + (n16 + 16) * SW + kc * 32 + q * 8);
      const bf16x8* wp = wv + (size_t)kc * 1024 + (size_t)(wid * 4) * 64 + lane;
#pragma unroll
      for (int j = 0; j < 4; j++) {
        bf16x8 bf = wp[j * 64];
        acc2[0][j] = __builtin_amdgcn_mfma_f32_16x16x32_bf16(af0, bf, acc2[0][j], 0, 0, 0);
        acc2[1][j] = __builtin_amdgcn_mfma_f32_16x16x32_bf16(af1, bf, acc2[1][j], 0, 0, 0);
      }
    }
#pragma unroll
    for (int a = 0; a < 2; a++) {
#pragma unroll
      for (int j = 0; j < 4; j++) {
        float bj = biasA[(wid * 4 + j) * 16 + n16];
#pragma unroll
        for (int r = 0; r < 4; r++) {
          float v = fmaxf(acc2[a][j][r] + bj, 0.f);
          brows[(a * 16 + q * 4 + r) * SW2 + (wid * 4 + j) * 16 + n16] = f2b(v);
        }
      }
    }
  }
  __syncthreads();

  f32x4 acc3[2][4];
#pragma unroll
  for (int a = 0; a < 2; a++)
#pragma unroll
    for (int j = 0; j < 4; j++) acc3[a][j] = f32x4{0.f, 0.f, 0.f, 0.f};
  const bf16x8* wv = reinterpret_cast<const bf16x8*>(wswB);
  for (int kc = 0; kc < HID / 32; kc++) {
    bf16x8 af0 = *reinterpret_cast<const bf16x8*>(brows + n16 * SW2 + kc * 32 + q * 8);
    bf16x8 af1 = *reinterpret_cast<const bf16x8*>(brows + (n16 + 16) * SW2 + kc * 32 + q * 8);
    const bf16x8* wp = wv + (size_t)kc * 1024 + (size_t)(wid * 4) * 64 + lane;
#pragma unroll
    for (int j = 0; j < 4; j++) {
      bf16x8 bf = wp[j * 64];
      acc3[0][j] = __builtin_amdgcn_mfma_f32_16x16x32_bf16(af0, bf, acc3[0][j], 0, 0, 0);
      acc3[1][j] = __builtin_amdgcn_mfma_f32_16x16x32_bf16(af1, bf, acc3[1][j], 0, 0, 0);
    }
  }
#pragma unroll
  for (int a = 0; a < 2; a++) {
    int mb = mblk + a * 16 + q * 4;
#pragma unroll
    for (int r = 0; r < 4; r++) {
      int m = mb + r;
      if (m < M) {
        unsigned char* dst = Bout + (size_t)m * HID + n16;
#pragma unroll
        for (int j = 0; j < 4; j++) {
          float v = acc3[a][j][r];
          unsigned int wbits = fp8_pk2<false>(v, v, 0u);
          dst[(wid * 4 + j) << 4] = (unsigned char)(wbits & 0xffu);
        }
      }
    }
  }
}

// -------- streaming single GEMM: N1(bf16) @ W2 -> fp8, 32 rows/block -------------------------
__global__ __launch_bounds__(256) void gemm2_kernel(const bf16_t* __restrict__ A,
                                                    const bf16_t* __restrict__ wsw,
                                                    unsigned char* __restrict__ Bout, int M) {
  constexpr int K  = HID;
  constexpr int SW = K + 8;
  __shared__ bf16_t arows[32 * SW];
  const int tid  = threadIdx.x;
  const int wid  = tid >> 6;
  const int lane = tid & 63;
  const int mblk = blockIdx.x * 32;

#pragma unroll
  for (int i = 0; i < 4; i++) {
    int idx = tid + i * 256;          // 0..1023
    int row = idx >> 5, u = idx & 31;
    if (mblk + row < M)
      *reinterpret_cast<uint4*>(arows + row * SW + u * 8) =
          *reinterpret_cast<const uint4*>(A + (size_t)(mblk + row) * K + u * 8);
  }
  __syncthreads();

  const int q = lane >> 4, n16 = lane & 15;
  f32x4 acc[2][4];
#pragma unroll
  for (int a = 0; a < 2; a++)
#pragma unroll
    for (int j = 0; j < 4; j++) acc[a][j] = f32x4{0.f, 0.f, 0.f, 0.f};
  const bf16x8* wv = reinterpret_cast<const bf16x8*>(wsw);
  for (int kc = 0; kc < K / 32; kc++) {
    bf16x8 af0 = *reinterpret_cast<const bf16x8*>(arows + n16 * SW + kc * 32 + q * 8);
    bf16x8 af1 = *reinterpret_cast<const bf16x8*>(arows + (n16 + 16) * SW + kc * 32 + q * 8);
    const bf16x8* wp = wv + (size_t)kc * 1024 + (size_t)(wid * 4) * 64 + lane;
#pragma unroll
    for (int j = 0; j < 4; j++) {
      bf16x8 bf = wp[j * 64];
      acc[0][j] = __builtin_amdgcn_mfma_f32_16x16x32_bf16(af0, bf, acc[0][j], 0, 0, 0);
      acc[1][j] = __builtin_amdgcn_mfma_f32_16x16x32_bf16(af1, bf, acc[1][j], 0, 0, 0);
    }
  }
#pragma unroll
  for (int a = 0; a < 2; a++) {
    int mb = mblk + a * 16 + q * 4;
#pragma unroll
    for (int r = 0; r < 4; r++) {
      int m = mb + r;
      if (m < M) {
        unsigned char* dst = Bout + (size_t)m * HID + n16;
#pragma unroll
        for (int j = 0; j < 4; j++) {
          float v = acc[a][j][r];
          unsigned int wbits = fp8_pk2<false>(v, v, 0u);
          dst[(wid * 4 + j) << 4] = (unsigned char)(wbits & 0xffu);
        }
      }
    }
  }
}

// ------------------------- pool: per (graph, 32-feature block), no atomics -------------------
__global__ __launch_bounds__(256) void pool_kernel(const bf16_t* __restrict__ N2,
                                                   const int* __restrict__ gstart,
                                                   float* __restrict__ pooled) {
  int g  = blockIdx.x >> 3;
  int fb = blockIdx.x & 7;
  int t  = threadIdx.x;
  int f  = fb * 32 + (t & 31);
  int np = t >> 5;                   // 0..7
  int s = gstart[g], e = gstart[g + 1];
  float acc = 0.f;
  for (int n = s + np; n < e; n += 8)
    acc += b2f(N2[(size_t)n * HID + f]);
  __shared__ float red[8][32];
  red[np][t & 31] = acc;
  __syncthreads();
  if (t < 32) {
    float s2 = 0.f;
#pragma unroll
    for (int p = 0; p < 8; p++) s2 += red[p][t];
    pooled[(size_t)g * HID + fb * 32 + t] = s2;   // SUM; head divides by count
  }
}

// ------------------------- head -------------------------
__global__ void head_kernel(const float* __restrict__ pooled, const int* __restrict__ gstart,
                            const float* __restrict__ M1, const float* __restrict__ bM1,
                            const float* __restrict__ M2, const float* __restrict__ bM2,
                            float* __restrict__ out) {
  int g = blockIdx.x;
  int t = threadIdx.x;
  __shared__ float p[HID];
  __shared__ float red[256];
  float cntf = (float)(gstart[g + 1] - gstart[g]);
  float inv = 1.f / fmaxf(cntf, 1.f);
  p[t] = pooled[(size_t)g * HID + t] * inv;
  __syncthreads();
  float h = bM1[t];
  for (int k = 0; k < HID; k++) h += p[k] * M1[k * HID + t];
  h = fmaxf(h, 0.f);
  float c0 = h * M2[t * OUTC + 0];
  float c1 = h * M2[t * OUTC + 1];
  red[t] = c0;
  __syncthreads();
  for (int off = 128; off > 0; off >>= 1) {
    if (t < off) red[t] += red[t + off];
    __syncthreads();
  }
  float s0 = 0.f;
  if (t == 0) s0 = red[0];
  __syncthreads();
  red[t] = c1;
  __syncthreads();
  for (int off = 128; off > 0; off >>= 1) {
    if (t < off) red[t] += red[t + off];
    __syncthreads();
  }
  if (t == 0) {
    out[g * 2 + 0] = s0 + bM2[0];
    out[g * 2 + 1] = red[0] + bM2[1];
  }
}

// ------------------------- launcher -------------------------
extern "C" void kernel_launch(void* const* d_in, const int* in_sizes, int n_in,
                              void* d_out, int out_size, void* d_ws, size_t ws_size,
                              hipStream_t stream) {
  const float* x   = (const float*)d_in[0];
  const int* ei    = (const int*)d_in[1];
  const int* rows  = ei;
  const int* cols  = ei + NNZV;
  const int* batch = (const int*)d_in[2];
  const float* W0  = (const float*)d_in[3];
  const float* b0  = (const float*)d_in[4];
  const float* W1  = (const float*)d_in[5];
  const float* b1  = (const float*)d_in[6];
  const float* W2  = (const float*)d_in[7];
  const float* b2  = (const float*)d_in[8];
  const float* M1  = (const float*)d_in[9];
  const float* bM1 = (const float*)d_in[10];
  const float* M2  = (const float*)d_in[11];
  const float* bM2 = (const float*)d_in[12];
  float* out       = (float*)d_out;

  // workspace layout
  char* w = (char*)d_ws;
  size_t off = 0;
  char* Preg = w + off; off += (size_t)NN * HID * 2;   // 25.6 MB: P8 fp8 / N2 bf16 (time-disjoint)
  char* Qreg = w + off; off += (size_t)NE * HID * 2;   // 25.6 MB: Qe8 / Q8 fp8
  char* Rreg = w + off; off += (size_t)NN * HID * 2;   // 25.6 MB: xb8+N0 / N1 (time-disjoint)
  bf16_t* wsw0 = (bf16_t*)(w + off); off += (size_t)INC * HID * 2;  // 64 KB
  bf16_t* wsw1 = (bf16_t*)(w + off); off += (size_t)HID * HID * 2;  // 128 KB
  bf16_t* wsw2 = (bf16_t*)(w + off); off += (size_t)HID * HID * 2;  // 128 KB
  int* gstart   = (int*)(w + off);   off += (size_t)(NG + 1) * 4;
  // ---- zero region start ----
  size_t zoff = off;
  float* pooled = (float*)(w + off); off += (size_t)NG * HID * 4;
  int* ncur     = (int*)(w + off);   off += (size_t)NN * 4;
  int* ecur     = (int*)(w + off);   off += (size_t)NE * 4;
  size_t zbytes = off - zoff;
  // ---- zero region end ----
  off = (off + 63) & ~(size_t)63;
  unsigned short* erow = (unsigned short*)(w + off); off += (size_t)NE * STRIDE * 2;  // 3.2 MB
  unsigned short* ncol = (unsigned short*)(w + off); off += (size_t)NN * STRIDE * 2;  // 3.2 MB

  // time-disjoint aliases:
  unsigned char* xb8 = (unsigned char*)Rreg;                  // fp8 x [NN][128]; dead after e0s
  bf16_t* N0 = (bf16_t*)(Rreg + (size_t)NN * INC);            // bf16 [NN][128]; lives with xb8
  bf16_t* N1 = (bf16_t*)Rreg;                                 // bf16 [NN][256]; after N0 dead
  unsigned char* Qe8 = (unsigned char*)Qreg;                  // fp8 [NE][128]
  unsigned char* Q8  = (unsigned char*)Qreg;                  // fp8 [NE][256]
  unsigned char* P8  = (unsigned char*)Preg;                  // fp8 [NN][256]
  bf16_t* N2 = (bf16_t*)Preg;                                 // bf16 [NN][256]; after P8 dead

  (void)hipMemsetAsync(w + zoff, 0, zbytes, stream);

  const int BN = 256;
  build_kernel<<<2 * FILL_B + PREP_BX + PREP_BW + PREP_BG, BN, 0, stream>>>(
      rows, cols, ncur, ecur, ncol, erow, x, xb8, W0, W1, W2, wsw0, wsw1, wsw2, batch, gstart);

  const int SG128 = 8 * ((NE + 255) / 256);   // 8 x 196
  const int SG256 = 8 * ((NE + 127) / 128);   // 8 x 391
  const int GG    = (NN + 31) / 32;           // 1563

  // layer 0: e0 sliced gather (fp8), n0 sliced gather (bf16), streaming GEMM W0+W1
  sgath_kernel<INC, true,  false><<<SG128, BN, 0, stream>>>(xb8, ecur, erow, nullptr, Qe8, NE);
  sgath_kernel<INC, false, false><<<SG128, BN, 0, stream>>>(Qe8, ncur, ncol, nullptr, N0, NN);
  gemm01_kernel<<<GG, BN, 0, stream>>>(N0, wsw0, b0, wsw1, P8, NN);
  // layer 1: e1 sliced, n1 sliced (+b1, relu), streaming GEMM W2
  sgath_kernel<HID, true,  false><<<SG256, BN, 0, stream>>>(P8, ecur, erow, nullptr, Q8, NE);
  sgath_kernel<HID, false, true ><<<SG256, BN, 0, stream>>>(Q8, ncur, ncol, b1, N1, NN);
  gemm2_kernel<<<GG, BN, 0, stream>>>(N1, wsw2, P8, NN);
  // layer 2: e2 sliced, n2 sliced (+b2, relu) -> N2, pool
  sgath_kernel<HID, true,  false><<<SG256, BN, 0, stream>>>(P8, ecur, erow, nullptr, Q8, NE);
  sgath_kernel<HID, false, true ><<<SG256, BN, 0, stream>>>(Q8, ncur, ncol, b2, N2, NN);
  pool_kernel<<<NG * 8, BN, 0, stream>>>(N2, gstart, pooled);

  head_kernel<<<NG, 256, 0, stream>>>(pooled, gstart, M1, bM1, M2, bM2, out);
}

// Round 7
// 355.729 us; speedup vs baseline: 1.4791x; 1.4791x over previous
//
#include <hip/hip_runtime.h>
#include <hip/hip_bf16.h>

#define NN   50000   // nodes
#define NE   50000   // hyperedges
#define NNZV 500000
#define NG   50
#define INC  128
#define HID  256
#define OUTC 2
#define STRIDE 32    // one aligned 64B line per segment

typedef __bf16 bf16_t;
typedef __bf16 bf16x8 __attribute__((ext_vector_type(8)));
typedef float  f32x4  __attribute__((ext_vector_type(4)));
typedef float  f32x2  __attribute__((ext_vector_type(2)));

__device__ __forceinline__ bf16_t f2b(float f) {
  union { __hip_bfloat16 h; bf16_t b; } u;
  u.h = __float2bfloat16(f);
  return u.b;
}
__device__ __forceinline__ float b2f(bf16_t b) { return (float)b; }

// fp8 e4m3 (OCP) pack/unpack; word-select must be an immediate -> template param.
template <bool HI>
__device__ __forceinline__ unsigned int fp8_pk2(float a, float b, unsigned int old) {
  return __builtin_amdgcn_cvt_pk_fp8_f32(a, b, old, HI);
}
__device__ __forceinline__ uint4 fp8_pk16(const float* v) {
  uint4 o;
  unsigned int* ow = &o.x;
#pragma unroll
  for (int wd = 0; wd < 4; wd++) {
    unsigned int u = fp8_pk2<false>(v[wd * 4 + 0], v[wd * 4 + 1], 0u);
    ow[wd] = fp8_pk2<true>(v[wd * 4 + 2], v[wd * 4 + 3], u);
  }
  return o;
}
__device__ __forceinline__ void fp8_acc16(uint4 v, f32x2* a2) {
  a2[0] += __builtin_amdgcn_cvt_pk_f32_fp8(v.x, false);
  a2[1] += __builtin_amdgcn_cvt_pk_f32_fp8(v.x, true);
  a2[2] += __builtin_amdgcn_cvt_pk_f32_fp8(v.y, false);
  a2[3] += __builtin_amdgcn_cvt_pk_f32_fp8(v.y, true);
  a2[4] += __builtin_amdgcn_cvt_pk_f32_fp8(v.z, false);
  a2[5] += __builtin_amdgcn_cvt_pk_f32_fp8(v.z, true);
  a2[6] += __builtin_amdgcn_cvt_pk_f32_fp8(v.w, false);
  a2[7] += __builtin_amdgcn_cvt_pk_f32_fp8(v.w, true);
}

// ------------------------- build: fill(x2) ∥ xcast(fp8) ∥ wswiz ∥ gstart ---------------------
// R4-proven structure (335.8us). R5 split and R6 slicing both regressed — keep this dispatch.
__device__ __forceinline__ void wswiz_one(const float* __restrict__ W, bf16_t* __restrict__ wsw, int t) {
  int lane = t & 63;
  int nt   = (t >> 6) & 15;
  int kc   = t >> 10;
  int q = lane >> 4, n16 = lane & 15;
  bf16x8 o;
#pragma unroll
  for (int j = 0; j < 8; j++)
    o[j] = f2b(W[(size_t)(kc * 32 + q * 8 + j) * HID + nt * 16 + n16]);
  reinterpret_cast<bf16x8*>(wsw)[t] = o;
}

// Batched fill: each thread loads 4 edges, issues 4 INDEPENDENT atomicAdds back-to-back
// (4 in flight per lane), one wait, then the 4 dependent scattered stores.
#define FILL_EPT   4
#define FILL_CHUNK (256 * FILL_EPT)                       // 1024 edges per block
#define FILL_B     ((NNZV + FILL_CHUNK - 1) / FILL_CHUNK) // 489 per side
#define PREP_BX 1563   // xcast blocks
#define PREP_BW 80     // wswiz blocks
#define PREP_BG 196    // gstart blocks

__device__ __forceinline__ void fill_side(const int* __restrict__ keys, const int* __restrict__ vals,
                                          int* __restrict__ cur, unsigned short* __restrict__ lstd,
                                          int local) {
  int base = local * FILL_CHUNK + threadIdx.x;
  int key[FILL_EPT], val[FILL_EPT], slot[FILL_EPT];
  bool ok[FILL_EPT];
#pragma unroll
  for (int e = 0; e < FILL_EPT; e++) {
    int i  = base + e * 256;
    ok[e]  = (i < NNZV);
    int ii = ok[e] ? i : 0;
    key[e] = keys[ii];
    val[e] = vals[ii];
  }
#pragma unroll
  for (int e = 0; e < FILL_EPT; e++)
    if (ok[e]) slot[e] = atomicAdd(&cur[key[e]], 1);
#pragma unroll
  for (int e = 0; e < FILL_EPT; e++)
    if (ok[e] && slot[e] < STRIDE)
      lstd[((size_t)key[e] << 5) + slot[e]] = (unsigned short)val[e];
}

__global__ void build_kernel(const int* __restrict__ rows, const int* __restrict__ cols,
                             int* __restrict__ ncur, int* __restrict__ ecur,
                             unsigned short* __restrict__ ncol, unsigned short* __restrict__ erow,
                             const float* __restrict__ x, unsigned char* __restrict__ xb8,
                             const float* __restrict__ W0, const float* __restrict__ W1,
                             const float* __restrict__ W2, bf16_t* __restrict__ w0,
                             bf16_t* __restrict__ w1, bf16_t* __restrict__ w2,
                             const int* __restrict__ batch, int* __restrict__ gstart) {
  int blk = blockIdx.x;
  if (blk < 2 * FILL_B) {
    if (blk < FILL_B) fill_side(cols, rows, ecur, erow, blk);             // edge-side
    else              fill_side(rows, cols, ncur, ncol, blk - FILL_B);    // node-side
  } else if (blk < 2 * FILL_B + PREP_BX) {
    int t = (blk - 2 * FILL_B) * 256 + threadIdx.x;
    if (t >= NN * INC / 16) return;
    const f32x4* p = reinterpret_cast<const f32x4*>(x) + (size_t)t * 4;
    float v[16];
#pragma unroll
    for (int wd = 0; wd < 4; wd++) {
      f32x4 q4 = p[wd];
#pragma unroll
      for (int j = 0; j < 4; j++) v[wd * 4 + j] = q4[j];
    }
    reinterpret_cast<uint4*>(xb8)[t] = fp8_pk16(v);
  } else if (blk < 2 * FILL_B + PREP_BX + PREP_BW) {
    int t = (blk - 2 * FILL_B - PREP_BX) * 256 + threadIdx.x;
    const int C0 = (INC / 32) * 1024;   // 4096
    const int C1 = (HID / 32) * 1024;   // 8192
    if (t < C0)                wswiz_one(W0, w0, t);
    else if (t < C0 + C1)      wswiz_one(W1, w1, t - C0);
    else if (t < C0 + 2 * C1)  wswiz_one(W2, w2, t - C0 - C1);
  } else {
    int i = (blk - 2 * FILL_B - PREP_BX - PREP_BW) * 256 + threadIdx.x;
    if (i >= NN) return;
    int cur  = batch[i];
    int prev = (i == 0) ? -1 : batch[i - 1];
    for (int g = prev + 1; g <= cur; g++) gstart[g] = i;
    if (i == NN - 1) {
      for (int g = cur + 1; g <= NG; g++) gstart[g] = NN;
    }
  }
}

// --------------- direct gather v2: single 64B list load + 2-deep batch prefetch --------------
// One LPR-lane group owns a whole segment; lane lr owns 16 fp8 features. The 32-entry list is
// exactly one cache line -> 4 independent dwordx4 upfront (one wait). Feature loads run in two
// 8-deep double-buffered batches (16 uint4 in flight) so a segment with c<=16 (97% at mean
// degree 10) pays ONE latency exposure. [R5-verified: ngemm<256> 53->48us vs v1]
template <int K>
__device__ __forceinline__ void gather_direct(const unsigned char* __restrict__ src,
                                              const int* __restrict__ cnt,
                                              const unsigned short* __restrict__ lst,
                                              int seg, int lr, float* acc, int& c) {
  constexpr int LPR = K / 16;
  c = min(cnt[seg], STRIDE);
  const uint4* lp = reinterpret_cast<const uint4*>(lst + ((size_t)seg << 5));
  uint4 la = lp[0], lb = lp[1], lc4 = lp[2], ld = lp[3];
  unsigned int lw[16] = {la.x, la.y, la.z, la.w, lb.x, lb.y, lb.z, lb.w,
                         lc4.x, lc4.y, lc4.z, lc4.w, ld.x, ld.y, ld.z, ld.w};
  const uint4* sv = reinterpret_cast<const uint4*>(src);
  f32x2* a2 = reinterpret_cast<f32x2*>(acc);
#pragma unroll
  for (int k = 0; k < 8; k++) a2[k] = f32x2{0.f, 0.f};
  uint4 v0[8], v1[8];
#define GADDR(j) ((size_t)((lw[(j) >> 1] >> (((j) & 1) * 16)) & 0xffffu) * LPR + lr)
#pragma unroll
  for (int j = 0; j < 8; j++) if (j < c) v0[j] = sv[GADDR(j)];
#pragma unroll
  for (int j = 0; j < 8; j++) if (8 + j < c) v1[j] = sv[GADDR(8 + j)];
#pragma unroll
  for (int j = 0; j < 8; j++) if (j < c) fp8_acc16(v0[j], a2);
#pragma unroll
  for (int j = 0; j < 8; j++) if (16 + j < c) v0[j] = sv[GADDR(16 + j)];
#pragma unroll
  for (int j = 0; j < 8; j++) if (8 + j < c) fp8_acc16(v1[j], a2);
#pragma unroll
  for (int j = 0; j < 8; j++) if (24 + j < c) v1[j] = sv[GADDR(24 + j)];
#pragma unroll
  for (int j = 0; j < 8; j++) if (16 + j < c) fp8_acc16(v0[j], a2);
#pragma unroll
  for (int j = 0; j < 8; j++) if (24 + j < c) fp8_acc16(v1[j], a2);
#undef GADDR
}

// ------------------------- standalone edge gather (fp8 -> fp8) -------------------------------
template <int W>
__global__ __launch_bounds__(256) void seg_gather_kernel(const unsigned char* __restrict__ src,
                                                         const int* __restrict__ cnt,
                                                         const unsigned short* __restrict__ lst,
                                                         unsigned char* __restrict__ dst, int nseg) {
  constexpr int LPR = W / 16;
  constexpr int SPW = 64 / LPR;        // segments per wave
  constexpr int SPB = 4 * SPW;         // segments per block
  const int lane = threadIdx.x & 63;
  const int wid  = threadIdx.x >> 6;
  const int sub  = lane / LPR, lr = lane % LPR;
  int seg = blockIdx.x * SPB + wid * SPW + sub;
  if (seg >= nseg) return;
  float acc[16];
  int c;
  gather_direct<W>(src, cnt, lst, seg, lr, acc, c);
  float sc = (c > 0) ? (1.0f / (float)c) : 0.f;
  float v16[16];
#pragma unroll
  for (int k = 0; k < 16; k++) v16[k] = acc[k] * sc;
  reinterpret_cast<uint4*>(dst + (size_t)seg * W + lr * 16)[0] = fp8_pk16(v16);
}

// ------------------------- fused node-gather + GEMM (16 rows/block) --------------------------
template <int K, bool GRELU, bool EPI, bool OUT8>
__global__ __launch_bounds__(256) void ngemm_kernel(const unsigned char* __restrict__ src,
                                                    const int* __restrict__ cnt,
                                                    const unsigned short* __restrict__ lst,
                                                    const float* __restrict__ gbias,
                                                    const bf16_t* __restrict__ wsw,
                                                    const float* __restrict__ ebias,
                                                    void* __restrict__ Bout, int M) {
  constexpr int SW = K + 8;   // padded LDS row stride (bf16), keeps 16B alignment
  __shared__ bf16_t arows[16 * SW];
  const int tid  = threadIdx.x;
  const int wid  = tid >> 6;
  const int lane = tid & 63;
  const int mblk = blockIdx.x * 16;

  // ---- phase 1: direct gather ----
  constexpr int LPR = K / 16;
  constexpr int SPW = 64 / LPR;
  const int sub = lane / LPR, lr = lane % LPR;
  {
    int row = wid * SPW + sub;
    int seg = mblk + row;
    if (seg < M) {
      float acc[16];
      int c;
      gather_direct<K>(src, cnt, lst, seg, lr, acc, c);
      float sc = (c > 0) ? (1.0f / (float)c) : 0.f;
      bf16_t* dp = arows + row * SW + lr * 16;
      bf16x8 o0, o1;
#pragma unroll
      for (int k = 0; k < 8; k++) {
        float v0 = acc[k] * sc, v1 = acc[k + 8] * sc;
        if constexpr (GRELU) {
          v0 = fmaxf(v0 + gbias[lr * 16 + k], 0.f);
          v1 = fmaxf(v1 + gbias[lr * 16 + k + 8], 0.f);
        }
        o0[k] = f2b(v0);
        o1[k] = f2b(v1);
      }
      reinterpret_cast<bf16x8*>(dp)[0] = o0;
      reinterpret_cast<bf16x8*>(dp)[1] = o1;
    }
  }
  __syncthreads();

  // ---- phase 2: GEMM 16 rows x 64 cols per wave ----
  const int q = lane >> 4, n16 = lane & 15;
  f32x4 acc2[4];
#pragma unroll
  for (int j = 0; j < 4; j++) acc2[j] = f32x4{0.f, 0.f, 0.f, 0.f};

  const bf16x8* wv = reinterpret_cast<const bf16x8*>(wsw);
  for (int kc = 0; kc < K / 32; kc++) {
    bf16x8 af = *reinterpret_cast<const bf16x8*>(arows + n16 * SW + kc * 32 + q * 8);
    const bf16x8* wp = wv + (size_t)kc * 1024 + (size_t)(wid * 4) * 64 + lane;
#pragma unroll
    for (int j = 0; j < 4; j++) {
      bf16x8 bf = wp[j * 64];
      acc2[j] = __builtin_amdgcn_mfma_f32_16x16x32_bf16(af, bf, acc2[j], 0, 0, 0);
    }
  }

  float bcol[4];
  if constexpr (EPI) {
#pragma unroll
    for (int j = 0; j < 4; j++) bcol[j] = ebias[(wid * 4 + j) * 16 + n16];
  }

  // C/D layout: col = lane&15, row = (lane>>4)*4 + reg
  int mb = mblk + q * 4;
#pragma unroll
  for (int r = 0; r < 4; r++) {
    int m = mb + r;
    if (m < M) {
      if constexpr (OUT8) {
        unsigned char* dst = (unsigned char*)Bout + (size_t)m * HID + n16;
#pragma unroll
        for (int j = 0; j < 4; j++) {
          float v = acc2[j][r];
          if constexpr (EPI) v = fmaxf(v + bcol[j], 0.f);
          unsigned int wbits = fp8_pk2<false>(v, v, 0u);
          dst[(wid * 4 + j) << 4] = (unsigned char)(wbits & 0xffu);
        }
      } else {
        bf16_t* dst = (bf16_t*)Bout + (size_t)m * HID + n16;
#pragma unroll
        for (int j = 0; j < 4; j++) {
          float v = acc2[j][r];
          if constexpr (EPI) v = fmaxf(v + bcol[j], 0.f);
          dst[(wid * 4 + j) << 4] = f2b(v);
        }
      }
    }
  }
}

// ------- fused node-gather + GEMM-W0(+b0,relu) + GEMM-W1 -> fp8, 32 rows/block (layer 0+1) ---
template <int K>
__global__ __launch_bounds__(256) void ngemm2_kernel(const unsigned char* __restrict__ src,
                                                     const int* __restrict__ cnt,
                                                     const unsigned short* __restrict__ lst,
                                                     const bf16_t* __restrict__ wswA,
                                                     const float* __restrict__ biasA,
                                                     const bf16_t* __restrict__ wswB,
                                                     unsigned char* __restrict__ Bout, int M) {
  constexpr int SW  = K + 8;
  constexpr int SW2 = HID + 8;
  constexpr int LPR = K / 16;      // 8
  constexpr int SPW = 64 / LPR;    // 8
  __shared__ bf16_t arows[32 * SW];
  __shared__ bf16_t brows[32 * SW2];
  const int tid  = threadIdx.x;
  const int wid  = tid >> 6;
  const int lane = tid & 63;
  const int mblk = blockIdx.x * 32;

  // ---- phase 1: direct gather (8 segments per wave) ----
  {
    const int sub = lane / LPR, lr = lane % LPR;
    int row = wid * SPW + sub;
    int seg = mblk + row;
    if (seg < M) {
      float acc[16];
      int c;
      gather_direct<K>(src, cnt, lst, seg, lr, acc, c);
      float sc = (c > 0) ? (1.0f / (float)c) : 0.f;
      bf16_t* dp = arows + row * SW + lr * 16;
      bf16x8 o0, o1;
#pragma unroll
      for (int k = 0; k < 8; k++) {
        o0[k] = f2b(acc[k] * sc);
        o1[k] = f2b(acc[k + 8] * sc);
      }
      reinterpret_cast<bf16x8*>(dp)[0] = o0;
      reinterpret_cast<bf16x8*>(dp)[1] = o1;
    }
  }
  __syncthreads();

  // ---- phase 2: GEMM W0, 32 rows x 64 cols per wave; relu(v+b0) -> brows ----
  const int q = lane >> 4, n16 = lane & 15;
  {
    f32x4 acc2[2][4];
#pragma unroll
    for (int a = 0; a < 2; a++)
#pragma unroll
      for (int j = 0; j < 4; j++) acc2[a][j] = f32x4{0.f, 0.f, 0.f, 0.f};
    const bf16x8* wv = reinterpret_cast<const bf16x8*>(wswA);
    for (int kc = 0; kc < K / 32; kc++) {
      bf16x8 af0 = *reinterpret_cast<const bf16x8*>(arows + n16 * SW + kc * 32 + q * 8);
      bf16x8 af1 = *reinterpret_cast<const bf16x8*>(arows + (n16 + 16) * SW + kc * 32 + q * 8);
      const bf16x8* wp = wv + (size_t)kc * 1024 + (size_t)(wid * 4) * 64 + lane;
#pragma unroll
      for (int j = 0; j < 4; j++) {
        bf16x8 bf = wp[j * 64];
        acc2[0][j] = __builtin_amdgcn_mfma_f32_16x16x32_bf16(af0, bf, acc2[0][j], 0, 0, 0);
        acc2[1][j] = __builtin_amdgcn_mfma_f32_16x16x32_bf16(af1, bf, acc2[1][j], 0, 0, 0);
      }
    }
#pragma unroll
    for (int a = 0; a < 2; a++) {
#pragma unroll
      for (int j = 0; j < 4; j++) {
        float bj = biasA[(wid * 4 + j) * 16 + n16];
#pragma unroll
        for (int r = 0; r < 4; r++) {
          float v = fmaxf(acc2[a][j][r] + bj, 0.f);
          brows[(a * 16 + q * 4 + r) * SW2 + (wid * 4 + j) * 16 + n16] = f2b(v);
        }
      }
    }
  }
  __syncthreads();

  // ---- phase 3: GEMM W1 (K=HID) -> fp8 out ----
  f32x4 acc3[2][4];
#pragma unroll
  for (int a = 0; a < 2; a++)
#pragma unroll
    for (int j = 0; j < 4; j++) acc3[a][j] = f32x4{0.f, 0.f, 0.f, 0.f};
  const bf16x8* wv = reinterpret_cast<const bf16x8*>(wswB);
  for (int kc = 0; kc < HID / 32; kc++) {
    bf16x8 af0 = *reinterpret_cast<const bf16x8*>(brows + n16 * SW2 + kc * 32 + q * 8);
    bf16x8 af1 = *reinterpret_cast<const bf16x8*>(brows + (n16 + 16) * SW2 + kc * 32 + q * 8);
    const bf16x8* wp = wv + (size_t)kc * 1024 + (size_t)(wid * 4) * 64 + lane;
#pragma unroll
    for (int j = 0; j < 4; j++) {
      bf16x8 bf = wp[j * 64];
      acc3[0][j] = __builtin_amdgcn_mfma_f32_16x16x32_bf16(af0, bf, acc3[0][j], 0, 0, 0);
      acc3[1][j] = __builtin_amdgcn_mfma_f32_16x16x32_bf16(af1, bf, acc3[1][j], 0, 0, 0);
    }
  }

#pragma unroll
  for (int a = 0; a < 2; a++) {
    int mb = mblk + a * 16 + q * 4;
#pragma unroll
    for (int r = 0; r < 4; r++) {
      int m = mb + r;
      if (m < M) {
        unsigned char* dst = Bout + (size_t)m * HID + n16;
#pragma unroll
        for (int j = 0; j < 4; j++) {
          float v = acc3[a][j][r];
          unsigned int wbits = fp8_pk2<false>(v, v, 0u);
          dst[(wid * 4 + j) << 4] = (unsigned char)(wbits & 0xffu);
        }
      }
    }
  }
}

// ------------------------- fused node-gather + pool (16 rows/block) --------------------------
__global__ __launch_bounds__(256) void npool_kernel(const unsigned char* __restrict__ src,
                                                    const int* __restrict__ cnt,
                                                    const unsigned short* __restrict__ lst,
                                                    const float* __restrict__ bias,
                                                    const int* __restrict__ batch,
                                                    float* __restrict__ pooled) {
  constexpr int K = HID, SW = K + 8;
  __shared__ bf16_t arows[16 * SW];
  const int tid  = threadIdx.x;
  const int wid  = tid >> 6;
  const int lane = tid & 63;
  const int mblk = blockIdx.x * 16;

  constexpr int LPR = K / 16;     // 16
  constexpr int SPW = 64 / LPR;   // 4
  const int sub = lane / LPR, lr = lane % LPR;
  {
    int row = wid * SPW + sub;
    int seg = mblk + row;
    if (seg < NN) {
      float acc[16];
      int c;
      gather_direct<K>(src, cnt, lst, seg, lr, acc, c);
      float sc = (c > 0) ? (1.0f / (float)c) : 0.f;
      bf16_t* dp = arows + row * SW + lr * 16;
      bf16x8 o0, o1;
#pragma unroll
      for (int k = 0; k < 8; k++) {
        o0[k] = f2b(fmaxf(acc[k] * sc + bias[lr * 16 + k], 0.f));
        o1[k] = f2b(fmaxf(acc[k + 8] * sc + bias[lr * 16 + k + 8], 0.f));
      }
      reinterpret_cast<bf16x8*>(dp)[0] = o0;
      reinterpret_cast<bf16x8*>(dp)[1] = o1;
    }
  }
  __syncthreads();

  // pool phase: thread f accumulates feature f over this block's 16 (sorted-batch) nodes
  int f = tid;
  float acc = 0.f;
  int curg = -1;
  for (int r = 0; r < 16; r++) {
    int node = mblk + r;
    if (node >= NN) break;
    int g = batch[node];
    if (g != curg) {
      if (curg >= 0) atomicAdd(&pooled[(size_t)curg * HID + f], acc);
      curg = g; acc = 0.f;
    }
    acc += b2f(arows[r * SW + f]);
  }
  if (curg >= 0) atomicAdd(&pooled[(size_t)curg * HID + f], acc);
}

// ------------------------- head -------------------------
__global__ void head_kernel(const float* __restrict__ pooled, const int* __restrict__ gstart,
                            const float* __restrict__ M1, const float* __restrict__ bM1,
                            const float* __restrict__ M2, const float* __restrict__ bM2,
                            float* __restrict__ out) {
  int g = blockIdx.x;
  int t = threadIdx.x;
  __shared__ float p[HID];
  __shared__ float red[256];
  float cntf = (float)(gstart[g + 1] - gstart[g]);
  float inv = 1.f / fmaxf(cntf, 1.f);
  p[t] = pooled[(size_t)g * HID + t] * inv;
  __syncthreads();
  float h = bM1[t];
  for (int k = 0; k < HID; k++) h += p[k] * M1[k * HID + t];
  h = fmaxf(h, 0.f);
  float c0 = h * M2[t * OUTC + 0];
  float c1 = h * M2[t * OUTC + 1];
  red[t] = c0;
  __syncthreads();
  for (int off = 128; off > 0; off >>= 1) {
    if (t < off) red[t] += red[t + off];
    __syncthreads();
  }
  float s0 = 0.f;
  if (t == 0) s0 = red[0];
  __syncthreads();
  red[t] = c1;
  __syncthreads();
  for (int off = 128; off > 0; off >>= 1) {
    if (t < off) red[t] += red[t + off];
    __syncthreads();
  }
  if (t == 0) {
    out[g * 2 + 0] = s0 + bM2[0];
    out[g * 2 + 1] = red[0] + bM2[1];
  }
}

// ------------------------- launcher -------------------------
extern "C" void kernel_launch(void* const* d_in, const int* in_sizes, int n_in,
                              void* d_out, int out_size, void* d_ws, size_t ws_size,
                              hipStream_t stream) {
  const float* x   = (const float*)d_in[0];
  const int* ei    = (const int*)d_in[1];
  const int* rows  = ei;
  const int* cols  = ei + NNZV;
  const int* batch = (const int*)d_in[2];
  const float* W0  = (const float*)d_in[3];
  const float* b0  = (const float*)d_in[4];
  const float* W1  = (const float*)d_in[5];
  const float* b1  = (const float*)d_in[6];
  const float* W2  = (const float*)d_in[7];
  const float* b2  = (const float*)d_in[8];
  const float* M1  = (const float*)d_in[9];
  const float* bM1 = (const float*)d_in[10];
  const float* M2  = (const float*)d_in[11];
  const float* bM2 = (const float*)d_in[12];
  float* out       = (float*)d_out;

  // workspace layout
  char* w = (char*)d_ws;
  size_t off = 0;
  bf16_t* P = (bf16_t*)(w + off); off += (size_t)NN * HID * 2;   // P8 (fp8 gemm outs)
  bf16_t* Q = (bf16_t*)(w + off); off += (size_t)NE * HID * 2;   // Qe8 / Q8
  bf16_t* R = (bf16_t*)(w + off); off += (size_t)NN * HID * 2;   // xb8 alias only
  bf16_t* wsw0 = (bf16_t*)(w + off); off += (size_t)INC * HID * 2;  // 64 KB
  bf16_t* wsw1 = (bf16_t*)(w + off); off += (size_t)HID * HID * 2;  // 128 KB
  bf16_t* wsw2 = (bf16_t*)(w + off); off += (size_t)HID * HID * 2;  // 128 KB
  int* gstart   = (int*)(w + off);   off += (size_t)(NG + 1) * 4;
  // ---- zero region start ----
  size_t zoff = off;
  float* pooled = (float*)(w + off); off += (size_t)NG * HID * 4;
  int* ncur     = (int*)(w + off);   off += (size_t)NN * 4;
  int* ecur     = (int*)(w + off);   off += (size_t)NE * 4;
  size_t zbytes = off - zoff;
  // ---- zero region end ----
  off = (off + 63) & ~(size_t)63;
  unsigned short* erow = (unsigned short*)(w + off); off += (size_t)NE * STRIDE * 2;  // 3.2 MB
  unsigned short* ncol = (unsigned short*)(w + off); off += (size_t)NN * STRIDE * 2;  // 3.2 MB

  // time-disjoint aliases:
  unsigned char* xb8 = (unsigned char*)R;   // fp8 x; dead after e0 gather
  unsigned char* Qe8 = (unsigned char*)Q;   // fp8 128-wide edge feats
  unsigned char* Q8  = (unsigned char*)Q;   // fp8 256-wide edge feats
  unsigned char* P8  = (unsigned char*)P;   // fp8 gemm outs (all layers)

  (void)hipMemsetAsync(w + zoff, 0, zbytes, stream);

  const int BN = 256;
  build_kernel<<<2 * FILL_B + PREP_BX + PREP_BW + PREP_BG, BN, 0, stream>>>(
      rows, cols, ncur, ecur, ncol, erow, x, xb8, W0, W1, W2, wsw0, wsw1, wsw2, batch, gstart);

  // layer 0+1 head: e0 gather, then fused [n0-gather + gemm-W0(b0,relu) + gemm-W1] -> P8
  seg_gather_kernel<INC><<<(NE + 31) / 32, BN, 0, stream>>>(xb8, ecur, erow, Qe8, NE);
  ngemm2_kernel<INC><<<(NN + 31) / 32, BN, 0, stream>>>(Qe8, ncur, ncol, wsw0, b0, wsw1, P8, NN);
  // layer 1 tail: e1 gather, then fused [n1-gather(b1,relu) + gemm-W2] -> P8
  seg_gather_kernel<HID><<<(NE + 15) / 16, BN, 0, stream>>>(P8, ecur, erow, Q8, NE);
  ngemm_kernel<HID, true, false, true><<<(NN + 15) / 16, BN, 0, stream>>>(
      Q8, ncur, ncol, b1, wsw2, nullptr, P8, NN);
  // layer 2: e2, then fused [n2-gather(b2,relu) + pool]
  seg_gather_kernel<HID><<<(NE + 15) / 16, BN, 0, stream>>>(P8, ecur, erow, Q8, NE);
  npool_kernel<<<(NN + 15) / 16, BN, 0, stream>>>(Q8, ncur, ncol, b2, batch, pooled);

  head_kernel<<<NG, 256, 0, stream>>>(pooled, gstart, M1, bM1, M2, bM2, out);
}

// Round 8
// 332.497 us; speedup vs baseline: 1.5824x; 1.0699x over previous
//
#include <hip/hip_runtime.h>
#include <hip/hip_bf16.h>

#define NN   50000   // nodes
#define NE   50000   // hyperedges
#define NNZV 500000
#define NG   50
#define INC  128
#define HID  256
#define OUTC 2
#define STRIDE 32    // one aligned 64B line per segment

typedef __bf16 bf16_t;
typedef __bf16 bf16x8 __attribute__((ext_vector_type(8)));
typedef float  f32x4  __attribute__((ext_vector_type(4)));
typedef float  f32x2  __attribute__((ext_vector_type(2)));

__device__ __forceinline__ bf16_t f2b(float f) {
  union { __hip_bfloat16 h; bf16_t b; } u;
  u.h = __float2bfloat16(f);
  return u.b;
}
__device__ __forceinline__ float b2f(bf16_t b) { return (float)b; }

// fp8 e4m3 (OCP) pack/unpack; word-select must be an immediate -> template param.
template <bool HI>
__device__ __forceinline__ unsigned int fp8_pk2(float a, float b, unsigned int old) {
  return __builtin_amdgcn_cvt_pk_fp8_f32(a, b, old, HI);
}
__device__ __forceinline__ uint4 fp8_pk16(const float* v) {
  uint4 o;
  unsigned int* ow = &o.x;
#pragma unroll
  for (int wd = 0; wd < 4; wd++) {
    unsigned int u = fp8_pk2<false>(v[wd * 4 + 0], v[wd * 4 + 1], 0u);
    ow[wd] = fp8_pk2<true>(v[wd * 4 + 2], v[wd * 4 + 3], u);
  }
  return o;
}
__device__ __forceinline__ void fp8_acc16(uint4 v, f32x2* a2) {
  a2[0] += __builtin_amdgcn_cvt_pk_f32_fp8(v.x, false);
  a2[1] += __builtin_amdgcn_cvt_pk_f32_fp8(v.x, true);
  a2[2] += __builtin_amdgcn_cvt_pk_f32_fp8(v.y, false);
  a2[3] += __builtin_amdgcn_cvt_pk_f32_fp8(v.y, true);
  a2[4] += __builtin_amdgcn_cvt_pk_f32_fp8(v.z, false);
  a2[5] += __builtin_amdgcn_cvt_pk_f32_fp8(v.z, true);
  a2[6] += __builtin_amdgcn_cvt_pk_f32_fp8(v.w, false);
  a2[7] += __builtin_amdgcn_cvt_pk_f32_fp8(v.w, true);
}

// ------------------------- build: vx-split fill ∥ xcast(fp8) ∥ wswiz ∥ gstart ----------------
// Fill structure: R0's vx-split (fastest measured: 53us vs 65-70 batched, 88 EPT=1).
// Each block scans a 512-edge chunk but only issues atomics for keys with (key&7)==vx:
// 16x redundant sequential reads (cheap) buy 15632 blocks of TLP, per-block atomic locality
// (1/8 of key space -> less same-line contention) and L2 store coalescing (WRITE 44 vs 67MB).
__device__ __forceinline__ void wswiz_one(const float* __restrict__ W, bf16_t* __restrict__ wsw, int t) {
  int lane = t & 63;
  int nt   = (t >> 6) & 15;
  int kc   = t >> 10;
  int q = lane >> 4, n16 = lane & 15;
  bf16x8 o;
#pragma unroll
  for (int j = 0; j < 8; j++)
    o[j] = f2b(W[(size_t)(kc * 32 + q * 8 + j) * HID + nt * 16 + n16]);
  reinterpret_cast<bf16x8*>(wsw)[t] = o;
}

#define FILL_EPT   2
#define FILL_CHUNK (256 * FILL_EPT)                       // 512 edges per chunk
#define FILL_NCH   ((NNZV + FILL_CHUNK - 1) / FILL_CHUNK) // 977
#define FILL_B     (FILL_NCH * 8)                         // 7816 (per side)
#define PREP_BX 1563   // xcast blocks
#define PREP_BW 80     // wswiz blocks
#define PREP_BG 196    // gstart blocks

__global__ void build_kernel(const int* __restrict__ rows, const int* __restrict__ cols,
                             int* __restrict__ ncur, int* __restrict__ ecur,
                             unsigned short* __restrict__ ncol, unsigned short* __restrict__ erow,
                             const float* __restrict__ x, unsigned char* __restrict__ xb8,
                             const float* __restrict__ W0, const float* __restrict__ W1,
                             const float* __restrict__ W2, bf16_t* __restrict__ w0,
                             bf16_t* __restrict__ w1, bf16_t* __restrict__ w2,
                             const int* __restrict__ batch, int* __restrict__ gstart) {
  int blk = blockIdx.x;
  if (blk < 2 * FILL_B) {
    bool ner = blk >= FILL_B;          // false: edge fill, true: node fill
    int local = ner ? blk - FILL_B : blk;
    int vx    = local & 7;
    int chunk = local >> 3;
    int base  = chunk * FILL_CHUNK + threadIdx.x;
#pragma unroll
    for (int e = 0; e < FILL_EPT; e++) {
      int i = base + e * 256;
      if (i < NNZV) {
        int r = rows[i], c = cols[i];
        if (!ner) {
          if ((c & 7) == vx) {
            int pe = atomicAdd(&ecur[c], 1);
            if (pe < STRIDE) erow[((size_t)c << 5) + pe] = (unsigned short)r;
          }
        } else {
          if ((r & 7) == vx) {
            int pn = atomicAdd(&ncur[r], 1);
            if (pn < STRIDE) ncol[((size_t)r << 5) + pn] = (unsigned short)c;
          }
        }
      }
    }
  } else if (blk < 2 * FILL_B + PREP_BX) {
    int t = (blk - 2 * FILL_B) * 256 + threadIdx.x;
    if (t >= NN * INC / 16) return;
    const f32x4* p = reinterpret_cast<const f32x4*>(x) + (size_t)t * 4;
    float v[16];
#pragma unroll
    for (int wd = 0; wd < 4; wd++) {
      f32x4 q4 = p[wd];
#pragma unroll
      for (int j = 0; j < 4; j++) v[wd * 4 + j] = q4[j];
    }
    reinterpret_cast<uint4*>(xb8)[t] = fp8_pk16(v);
  } else if (blk < 2 * FILL_B + PREP_BX + PREP_BW) {
    int t = (blk - 2 * FILL_B - PREP_BX) * 256 + threadIdx.x;
    const int C0 = (INC / 32) * 1024;   // 4096
    const int C1 = (HID / 32) * 1024;   // 8192
    if (t < C0)                wswiz_one(W0, w0, t);
    else if (t < C0 + C1)      wswiz_one(W1, w1, t - C0);
    else if (t < C0 + 2 * C1)  wswiz_one(W2, w2, t - C0 - C1);
  } else {
    int i = (blk - 2 * FILL_B - PREP_BX - PREP_BW) * 256 + threadIdx.x;
    if (i >= NN) return;
    int cur  = batch[i];
    int prev = (i == 0) ? -1 : batch[i - 1];
    for (int g = prev + 1; g <= cur; g++) gstart[g] = i;
    if (i == NN - 1) {
      for (int g = cur + 1; g <= NG; g++) gstart[g] = NN;
    }
  }
}

// --------------- direct gather v1: one LPR-lane group owns a whole segment -------------------
// lane lr owns features lr*16..lr*16+15 (fp8 bytes); loops over all <=32 entries, 8-deep
// load batches. Low VGPR (48) -> occupancy ~40%; R7 proved the deeper v2 variant's VGPR cost
// (64+, occ 31%) loses more TLP latency-hiding than its ILP gains.
template <int K>
__device__ __forceinline__ void gather_direct(const unsigned char* __restrict__ src,
                                              const int* __restrict__ cnt,
                                              const unsigned short* __restrict__ lst,
                                              int seg, int lr, float* acc, int& c) {
  constexpr int LPR = K / 16;
  c = min(cnt[seg], STRIDE);
  const unsigned short* p = lst + ((size_t)seg << 5);
  const uint4* sv = reinterpret_cast<const uint4*>(src);
  f32x2* a2 = reinterpret_cast<f32x2*>(acc);
#pragma unroll
  for (int k = 0; k < 8; k++) a2[k] = f32x2{0.f, 0.f};
  for (int i0 = 0; i0 < c; i0 += 8) {
    int m = c - i0;
    uint4 v[8];
#pragma unroll
    for (int j = 0; j < 8; j++)
      if (j < m) v[j] = sv[(size_t)p[i0 + j] * LPR + lr];
#pragma unroll
    for (int j = 0; j < 8; j++)
      if (j < m) fp8_acc16(v[j], a2);
  }
}

// ------------------------- standalone edge gather (fp8 -> fp8) -------------------------------
template <int W>
__global__ __launch_bounds__(256) void seg_gather_kernel(const unsigned char* __restrict__ src,
                                                         const int* __restrict__ cnt,
                                                         const unsigned short* __restrict__ lst,
                                                         unsigned char* __restrict__ dst, int nseg) {
  constexpr int LPR = W / 16;
  constexpr int SPW = 64 / LPR;        // segments per wave
  constexpr int SPB = 4 * SPW;         // segments per block
  const int lane = threadIdx.x & 63;
  const int wid  = threadIdx.x >> 6;
  const int sub  = lane / LPR, lr = lane % LPR;
  int seg = blockIdx.x * SPB + wid * SPW + sub;
  if (seg >= nseg) return;
  float acc[16];
  int c;
  gather_direct<W>(src, cnt, lst, seg, lr, acc, c);
  float sc = (c > 0) ? (1.0f / (float)c) : 0.f;
  float v16[16];
#pragma unroll
  for (int k = 0; k < 16; k++) v16[k] = acc[k] * sc;
  reinterpret_cast<uint4*>(dst + (size_t)seg * W + lr * 16)[0] = fp8_pk16(v16);
}

// ------------------------- fused node-gather + GEMM (16 rows/block) --------------------------
template <int K, bool GRELU, bool EPI, bool OUT8>
__global__ __launch_bounds__(256) void ngemm_kernel(const unsigned char* __restrict__ src,
                                                    const int* __restrict__ cnt,
                                                    const unsigned short* __restrict__ lst,
                                                    const float* __restrict__ gbias,
                                                    const bf16_t* __restrict__ wsw,
                                                    const float* __restrict__ ebias,
                                                    void* __restrict__ Bout, int M) {
  constexpr int SW = K + 8;   // padded LDS row stride (bf16), keeps 16B alignment
  __shared__ bf16_t arows[16 * SW];
  const int tid  = threadIdx.x;
  const int wid  = tid >> 6;
  const int lane = tid & 63;
  const int mblk = blockIdx.x * 16;

  // ---- phase 1: direct gather ----
  constexpr int LPR = K / 16;
  constexpr int SPW = 64 / LPR;
  const int sub = lane / LPR, lr = lane % LPR;
  {
    int row = wid * SPW + sub;
    int seg = mblk + row;
    if (seg < M) {
      float acc[16];
      int c;
      gather_direct<K>(src, cnt, lst, seg, lr, acc, c);
      float sc = (c > 0) ? (1.0f / (float)c) : 0.f;
      bf16_t* dp = arows + row * SW + lr * 16;
      bf16x8 o0, o1;
#pragma unroll
      for (int k = 0; k < 8; k++) {
        float v0 = acc[k] * sc, v1 = acc[k + 8] * sc;
        if constexpr (GRELU) {
          v0 = fmaxf(v0 + gbias[lr * 16 + k], 0.f);
          v1 = fmaxf(v1 + gbias[lr * 16 + k + 8], 0.f);
        }
        o0[k] = f2b(v0);
        o1[k] = f2b(v1);
      }
      reinterpret_cast<bf16x8*>(dp)[0] = o0;
      reinterpret_cast<bf16x8*>(dp)[1] = o1;
    }
  }
  __syncthreads();

  // ---- phase 2: GEMM 16 rows x 64 cols per wave ----
  const int q = lane >> 4, n16 = lane & 15;
  f32x4 acc2[4];
#pragma unroll
  for (int j = 0; j < 4; j++) acc2[j] = f32x4{0.f, 0.f, 0.f, 0.f};

  const bf16x8* wv = reinterpret_cast<const bf16x8*>(wsw);
  for (int kc = 0; kc < K / 32; kc++) {
    bf16x8 af = *reinterpret_cast<const bf16x8*>(arows + n16 * SW + kc * 32 + q * 8);
    const bf16x8* wp = wv + (size_t)kc * 1024 + (size_t)(wid * 4) * 64 + lane;
#pragma unroll
    for (int j = 0; j < 4; j++) {
      bf16x8 bf = wp[j * 64];
      acc2[j] = __builtin_amdgcn_mfma_f32_16x16x32_bf16(af, bf, acc2[j], 0, 0, 0);
    }
  }

  float bcol[4];
  if constexpr (EPI) {
#pragma unroll
    for (int j = 0; j < 4; j++) bcol[j] = ebias[(wid * 4 + j) * 16 + n16];
  }

  // C/D layout: col = lane&15, row = (lane>>4)*4 + reg
  int mb = mblk + q * 4;
#pragma unroll
  for (int r = 0; r < 4; r++) {
    int m = mb + r;
    if (m < M) {
      if constexpr (OUT8) {
        unsigned char* dst = (unsigned char*)Bout + (size_t)m * HID + n16;
#pragma unroll
        for (int j = 0; j < 4; j++) {
          float v = acc2[j][r];
          if constexpr (EPI) v = fmaxf(v + bcol[j], 0.f);
          unsigned int wbits = fp8_pk2<false>(v, v, 0u);
          dst[(wid * 4 + j) << 4] = (unsigned char)(wbits & 0xffu);
        }
      } else {
        bf16_t* dst = (bf16_t*)Bout + (size_t)m * HID + n16;
#pragma unroll
        for (int j = 0; j < 4; j++) {
          float v = acc2[j][r];
          if constexpr (EPI) v = fmaxf(v + bcol[j], 0.f);
          dst[(wid * 4 + j) << 4] = f2b(v);
        }
      }
    }
  }
}

// ------- fused node-gather + GEMM-W0(+b0,relu) + GEMM-W1 -> fp8, 32 rows/block (layer 0+1) ---
template <int K>
__global__ __launch_bounds__(256) void ngemm2_kernel(const unsigned char* __restrict__ src,
                                                     const int* __restrict__ cnt,
                                                     const unsigned short* __restrict__ lst,
                                                     const bf16_t* __restrict__ wswA,
                                                     const float* __restrict__ biasA,
                                                     const bf16_t* __restrict__ wswB,
                                                     unsigned char* __restrict__ Bout, int M) {
  constexpr int SW  = K + 8;
  constexpr int SW2 = HID + 8;
  constexpr int LPR = K / 16;      // 8
  constexpr int SPW = 64 / LPR;    // 8
  __shared__ bf16_t arows[32 * SW];
  __shared__ bf16_t brows[32 * SW2];
  const int tid  = threadIdx.x;
  const int wid  = tid >> 6;
  const int lane = tid & 63;
  const int mblk = blockIdx.x * 32;

  // ---- phase 1: direct gather (8 segments per wave) ----
  {
    const int sub = lane / LPR, lr = lane % LPR;
    int row = wid * SPW + sub;
    int seg = mblk + row;
    if (seg < M) {
      float acc[16];
      int c;
      gather_direct<K>(src, cnt, lst, seg, lr, acc, c);
      float sc = (c > 0) ? (1.0f / (float)c) : 0.f;
      bf16_t* dp = arows + row * SW + lr * 16;
      bf16x8 o0, o1;
#pragma unroll
      for (int k = 0; k < 8; k++) {
        o0[k] = f2b(acc[k] * sc);
        o1[k] = f2b(acc[k + 8] * sc);
      }
      reinterpret_cast<bf16x8*>(dp)[0] = o0;
      reinterpret_cast<bf16x8*>(dp)[1] = o1;
    }
  }
  __syncthreads();

  // ---- phase 2: GEMM W0, 32 rows x 64 cols per wave; relu(v+b0) -> brows ----
  const int q = lane >> 4, n16 = lane & 15;
  {
    f32x4 acc2[2][4];
#pragma unroll
    for (int a = 0; a < 2; a++)
#pragma unroll
      for (int j = 0; j < 4; j++) acc2[a][j] = f32x4{0.f, 0.f, 0.f, 0.f};
    const bf16x8* wv = reinterpret_cast<const bf16x8*>(wswA);
    for (int kc = 0; kc < K / 32; kc++) {
      bf16x8 af0 = *reinterpret_cast<const bf16x8*>(arows + n16 * SW + kc * 32 + q * 8);
      bf16x8 af1 = *reinterpret_cast<const bf16x8*>(arows + (n16 + 16) * SW + kc * 32 + q * 8);
      const bf16x8* wp = wv + (size_t)kc * 1024 + (size_t)(wid * 4) * 64 + lane;
#pragma unroll
      for (int j = 0; j < 4; j++) {
        bf16x8 bf = wp[j * 64];
        acc2[0][j] = __builtin_amdgcn_mfma_f32_16x16x32_bf16(af0, bf, acc2[0][j], 0, 0, 0);
        acc2[1][j] = __builtin_amdgcn_mfma_f32_16x16x32_bf16(af1, bf, acc2[1][j], 0, 0, 0);
      }
    }
#pragma unroll
    for (int a = 0; a < 2; a++) {
#pragma unroll
      for (int j = 0; j < 4; j++) {
        float bj = biasA[(wid * 4 + j) * 16 + n16];
#pragma unroll
        for (int r = 0; r < 4; r++) {
          float v = fmaxf(acc2[a][j][r] + bj, 0.f);
          brows[(a * 16 + q * 4 + r) * SW2 + (wid * 4 + j) * 16 + n16] = f2b(v);
        }
      }
    }
  }
  __syncthreads();

  // ---- phase 3: GEMM W1 (K=HID) -> fp8 out ----
  f32x4 acc3[2][4];
#pragma unroll
  for (int a = 0; a < 2; a++)
#pragma unroll
    for (int j = 0; j < 4; j++) acc3[a][j] = f32x4{0.f, 0.f, 0.f, 0.f};
  const bf16x8* wv = reinterpret_cast<const bf16x8*>(wswB);
  for (int kc = 0; kc < HID / 32; kc++) {
    bf16x8 af0 = *reinterpret_cast<const bf16x8*>(brows + n16 * SW2 + kc * 32 + q * 8);
    bf16x8 af1 = *reinterpret_cast<const bf16x8*>(brows + (n16 + 16) * SW2 + kc * 32 + q * 8);
    const bf16x8* wp = wv + (size_t)kc * 1024 + (size_t)(wid * 4) * 64 + lane;
#pragma unroll
    for (int j = 0; j < 4; j++) {
      bf16x8 bf = wp[j * 64];
      acc3[0][j] = __builtin_amdgcn_mfma_f32_16x16x32_bf16(af0, bf, acc3[0][j], 0, 0, 0);
      acc3[1][j] = __builtin_amdgcn_mfma_f32_16x16x32_bf16(af1, bf, acc3[1][j], 0, 0, 0);
    }
  }

#pragma unroll
  for (int a = 0; a < 2; a++) {
    int mb = mblk + a * 16 + q * 4;
#pragma unroll
    for (int r = 0; r < 4; r++) {
      int m = mb + r;
      if (m < M) {
        unsigned char* dst = Bout + (size_t)m * HID + n16;
#pragma unroll
        for (int j = 0; j < 4; j++) {
          float v = acc3[a][j][r];
          unsigned int wbits = fp8_pk2<false>(v, v, 0u);
          dst[(wid * 4 + j) << 4] = (unsigned char)(wbits & 0xffu);
        }
      }
    }
  }
}

// ------------------------- fused node-gather + pool (16 rows/block) --------------------------
__global__ __launch_bounds__(256) void npool_kernel(const unsigned char* __restrict__ src,
                                                    const int* __restrict__ cnt,
                                                    const unsigned short* __restrict__ lst,
                                                    const float* __restrict__ bias,
                                                    const int* __restrict__ batch,
                                                    float* __restrict__ pooled) {
  constexpr int K = HID, SW = K + 8;
  __shared__ bf16_t arows[16 * SW];
  const int tid  = threadIdx.x;
  const int wid  = tid >> 6;
  const int lane = tid & 63;
  const int mblk = blockIdx.x * 16;

  constexpr int LPR = K / 16;     // 16
  constexpr int SPW = 64 / LPR;   // 4
  const int sub = lane / LPR, lr = lane % LPR;
  {
    int row = wid * SPW + sub;
    int seg = mblk + row;
    if (seg < NN) {
      float acc[16];
      int c;
      gather_direct<K>(src, cnt, lst, seg, lr, acc, c);
      float sc = (c > 0) ? (1.0f / (float)c) : 0.f;
      bf16_t* dp = arows + row * SW + lr * 16;
      bf16x8 o0, o1;
#pragma unroll
      for (int k = 0; k < 8; k++) {
        o0[k] = f2b(fmaxf(acc[k] * sc + bias[lr * 16 + k], 0.f));
        o1[k] = f2b(fmaxf(acc[k + 8] * sc + bias[lr * 16 + k + 8], 0.f));
      }
      reinterpret_cast<bf16x8*>(dp)[0] = o0;
      reinterpret_cast<bf16x8*>(dp)[1] = o1;
    }
  }
  __syncthreads();

  // pool phase: thread f accumulates feature f over this block's 16 (sorted-batch) nodes
  int f = tid;
  float acc = 0.f;
  int curg = -1;
  for (int r = 0; r < 16; r++) {
    int node = mblk + r;
    if (node >= NN) break;
    int g = batch[node];
    if (g != curg) {
      if (curg >= 0) atomicAdd(&pooled[(size_t)curg * HID + f], acc);
      curg = g; acc = 0.f;
    }
    acc += b2f(arows[r * SW + f]);
  }
  if (curg >= 0) atomicAdd(&pooled[(size_t)curg * HID + f], acc);
}

// ------------------------- head -------------------------
__global__ void head_kernel(const float* __restrict__ pooled, const int* __restrict__ gstart,
                            const float* __restrict__ M1, const float* __restrict__ bM1,
                            const float* __restrict__ M2, const float* __restrict__ bM2,
                            float* __restrict__ out) {
  int g = blockIdx.x;
  int t = threadIdx.x;
  __shared__ float p[HID];
  __shared__ float red[256];
  float cntf = (float)(gstart[g + 1] - gstart[g]);
  float inv = 1.f / fmaxf(cntf, 1.f);
  p[t] = pooled[(size_t)g * HID + t] * inv;
  __syncthreads();
  float h = bM1[t];
  for (int k = 0; k < HID; k++) h += p[k] * M1[k * HID + t];
  h = fmaxf(h, 0.f);
  float c0 = h * M2[t * OUTC + 0];
  float c1 = h * M2[t * OUTC + 1];
  red[t] = c0;
  __syncthreads();
  for (int off = 128; off > 0; off >>= 1) {
    if (t < off) red[t] += red[t + off];
    __syncthreads();
  }
  float s0 = 0.f;
  if (t == 0) s0 = red[0];
  __syncthreads();
  red[t] = c1;
  __syncthreads();
  for (int off = 128; off > 0; off >>= 1) {
    if (t < off) red[t] += red[t + off];
    __syncthreads();
  }
  if (t == 0) {
    out[g * 2 + 0] = s0 + bM2[0];
    out[g * 2 + 1] = red[0] + bM2[1];
  }
}

// ------------------------- launcher -------------------------
extern "C" void kernel_launch(void* const* d_in, const int* in_sizes, int n_in,
                              void* d_out, int out_size, void* d_ws, size_t ws_size,
                              hipStream_t stream) {
  const float* x   = (const float*)d_in[0];
  const int* ei    = (const int*)d_in[1];
  const int* rows  = ei;
  const int* cols  = ei + NNZV;
  const int* batch = (const int*)d_in[2];
  const float* W0  = (const float*)d_in[3];
  const float* b0  = (const float*)d_in[4];
  const float* W1  = (const float*)d_in[5];
  const float* b1  = (const float*)d_in[6];
  const float* W2  = (const float*)d_in[7];
  const float* b2  = (const float*)d_in[8];
  const float* M1  = (const float*)d_in[9];
  const float* bM1 = (const float*)d_in[10];
  const float* M2  = (const float*)d_in[11];
  const float* bM2 = (const float*)d_in[12];
  float* out       = (float*)d_out;

  // workspace layout
  char* w = (char*)d_ws;
  size_t off = 0;
  bf16_t* P = (bf16_t*)(w + off); off += (size_t)NN * HID * 2;   // P8 (fp8 gemm outs)
  bf16_t* Q = (bf16_t*)(w + off); off += (size_t)NE * HID * 2;   // Qe8 / Q8
  bf16_t* R = (bf16_t*)(w + off); off += (size_t)NN * HID * 2;   // xb8 alias only
  bf16_t* wsw0 = (bf16_t*)(w + off); off += (size_t)INC * HID * 2;  // 64 KB
  bf16_t* wsw1 = (bf16_t*)(w + off); off += (size_t)HID * HID * 2;  // 128 KB
  bf16_t* wsw2 = (bf16_t*)(w + off); off += (size_t)HID * HID * 2;  // 128 KB
  int* gstart   = (int*)(w + off);   off += (size_t)(NG + 1) * 4;
  // ---- zero region start ----
  size_t zoff = off;
  float* pooled = (float*)(w + off); off += (size_t)NG * HID * 4;
  int* ncur     = (int*)(w + off);   off += (size_t)NN * 4;
  int* ecur     = (int*)(w + off);   off += (size_t)NE * 4;
  size_t zbytes = off - zoff;
  // ---- zero region end ----
  off = (off + 63) & ~(size_t)63;
  unsigned short* erow = (unsigned short*)(w + off); off += (size_t)NE * STRIDE * 2;  // 3.2 MB
  unsigned short* ncol = (unsigned short*)(w + off); off += (size_t)NN * STRIDE * 2;  // 3.2 MB

  // time-disjoint aliases:
  unsigned char* xb8 = (unsigned char*)R;   // fp8 x; dead after e0 gather
  unsigned char* Qe8 = (unsigned char*)Q;   // fp8 128-wide edge feats
  unsigned char* Q8  = (unsigned char*)Q;   // fp8 256-wide edge feats
  unsigned char* P8  = (unsigned char*)P;   // fp8 gemm outs (all layers)

  (void)hipMemsetAsync(w + zoff, 0, zbytes, stream);

  const int BN = 256;
  build_kernel<<<2 * FILL_B + PREP_BX + PREP_BW + PREP_BG, BN, 0, stream>>>(
      rows, cols, ncur, ecur, ncol, erow, x, xb8, W0, W1, W2, wsw0, wsw1, wsw2, batch, gstart);

  // layer 0+1 head: e0 gather, then fused [n0-gather + gemm-W0(b0,relu) + gemm-W1] -> P8
  seg_gather_kernel<INC><<<(NE + 31) / 32, BN, 0, stream>>>(xb8, ecur, erow, Qe8, NE);
  ngemm2_kernel<INC><<<(NN + 31) / 32, BN, 0, stream>>>(Qe8, ncur, ncol, wsw0, b0, wsw1, P8, NN);
  // layer 1 tail: e1 gather, then fused [n1-gather(b1,relu) + gemm-W2] -> P8
  seg_gather_kernel<HID><<<(NE + 15) / 16, BN, 0, stream>>>(P8, ecur, erow, Q8, NE);
  ngemm_kernel<HID, true, false, true><<<(NN + 15) / 16, BN, 0, stream>>>(
      Q8, ncur, ncol, b1, wsw2, nullptr, P8, NN);
  // layer 2: e2, then fused [n2-gather(b2,relu) + pool]
  seg_gather_kernel<HID><<<(NE + 15) / 16, BN, 0, stream>>>(P8, ecur, erow, Q8, NE);
  npool_kernel<<<(NN + 15) / 16, BN, 0, stream>>>(Q8, ncur, ncol, b2, batch, pooled);

  head_kernel<<<NG, 256, 0, stream>>>(pooled, gstart, M1, bM1, M2, bM2, out);
}